// Round 5
// baseline (275.856 us; speedup 1.0000x reference)
//
#include <hip/hip_runtime.h>

// LearnedQueryAttention: B=8, L=4096, KD=512, ED=1024, H=8. All I/O fp32.
// Raw-reshape semantics: head h owns the contiguous flat slab
// f = h*(L+1)*(C/H) + row*(C/H) + d of per-batch [X_flat | bias]; only
// f >= L*C touches the bias token (head 7, rows 4089..4095 here). Row-aligned
// pointer select is exact for both K (64 f/row) and V (128 f/row).
//
// Round notes (this revision):
//  - R4 post-mortem: 4 one-shot-block variants all ~2.5 TB/s while the
//    poison fill streams 6.9 TB/s in the same capture. Remaining delta:
//    burst-then-stall duty cycle + 4096-block churn. This round k1 is a
//    LONG-LIVED SOFTWARE-PIPELINED STREAMER:
//    * grid (16,64) = 1024 blocks = exactly 4/CU, one residency round.
//    * each wave owns 64 rows, 8 iters x 8 rows (3 KB/iter), explicit
//      2-stage rotation with NAMED A/B registers (cannot be re-serialized)
//      + sched_barrier(0) fences: LOAD(i+1) always issues before COMPUTE(i).
//    * no __syncthreads in the loop -> compiler emits counted vmcnt waits
//      (rolling window, never drains).
//    * verification: VGPR_Count must be ~90-110; if so and k1 still >=70us,
//      ~2.5 TB/s is a real pattern ceiling -> declare floor.
//  - m=0 softmax frame retained (|scores|<~1): no max pass, partials sum
//    directly. Row 4096 handled analytically in kernel 2.
#define BATCH 8
#define LSEQ  4096
#define LP    4097
#define KDIM  512
#define EDIM  1024
#define NH    8
#define DK    64
#define DV    128
#define NG    64          // B*H groups
#define NCH   16          // chunks per group (256 rows each)
#define KLIM  (LSEQ * KDIM)
#define VLIM  (LSEQ * EDIM)
#define LN_EPS 1e-5f

typedef float floatx4 __attribute__((ext_vector_type(4)));

// ---- per-stage load: 2 K-rows/group + 4 V-row-pairs + 4 w/b scalars ----
#define STAGE_LOAD(S, rr) do {                                              \
    const int rk0 = (rr) + gid;                                             \
    const int rk1 = (rr) + 4 + gid;                                         \
    const int f0 = fheadk + rk0 * DK;                                       \
    const int f1 = fheadk + rk1 * DK;                                       \
    const float* p0 = (f0 < KLIM) ? (kp + f0) : (k_bias + (f0 - KLIM));     \
    const float* p1 = (f1 < KLIM) ? (kp + f1) : (k_bias + (f1 - KLIM));     \
    kv0##S = *reinterpret_cast<const floatx4*>(p0 + l16 * 4);               \
    kv1##S = *reinterpret_cast<const floatx4*>(p1 + l16 * 4);               \
    wv0##S = wptr[rk0]; bv0##S = bptr[rk0];                                 \
    wv1##S = wptr[rk1]; bv1##S = bptr[rk1];                                 \
    _Pragma("unroll")                                                       \
    for (int j = 0; j < 4; ++j) {                                           \
        const int fv = fheadv + ((rr) + 2 * j + hi) * DV;                   \
        const float* pv = (fv < VLIM) ? (vp + fv) : (v_bias + (fv - VLIM)); \
        vv##S[j] = *reinterpret_cast<const floatx4*>(pv + d0);              \
    }                                                                       \
} while (0)

// ---- per-stage compute: dot+butterfly+exp, broadcast, 16 FMA ----
#define STAGE_COMPUTE(S) do {                                               \
    float s0 = q.x * kv0##S.x + q.y * kv0##S.y + q.z * kv0##S.z + q.w * kv0##S.w; \
    float s1 = q.x * kv1##S.x + q.y * kv1##S.y + q.z * kv1##S.z + q.w * kv1##S.w; \
    s0 += __shfl_xor(s0, 1); s1 += __shfl_xor(s1, 1);                       \
    s0 += __shfl_xor(s0, 2); s1 += __shfl_xor(s1, 2);                       \
    s0 += __shfl_xor(s0, 4); s1 += __shfl_xor(s1, 4);                       \
    s0 += __shfl_xor(s0, 8); s1 += __shfl_xor(s1, 8);                       \
    const float e0 = __expf(s0 * wv0##S + bv0##S);                          \
    const float e1 = __expf(s1 * wv1##S + bv1##S);                          \
    z += e0 + e1;                                                           \
    const float w0 = __shfl(e0, 16 * hi, 64);                               \
    const float w1 = __shfl(e0, 16 * (2 + hi), 64);                         \
    const float w2 = __shfl(e1, 16 * hi, 64);                               \
    const float w3 = __shfl(e1, 16 * (2 + hi), 64);                         \
    a0 += w0 * vv##S[0].x; a1 += w0 * vv##S[0].y;                           \
    a2 += w0 * vv##S[0].z; a3 += w0 * vv##S[0].w;                           \
    a0 += w1 * vv##S[1].x; a1 += w1 * vv##S[1].y;                           \
    a2 += w1 * vv##S[1].z; a3 += w1 * vv##S[1].w;                           \
    a0 += w2 * vv##S[2].x; a1 += w2 * vv##S[2].y;                           \
    a2 += w2 * vv##S[2].z; a3 += w2 * vv##S[2].w;                           \
    a0 += w3 * vv##S[3].x; a1 += w3 * vv##S[3].y;                           \
    a2 += w3 * vv##S[3].z; a3 += w3 * vv##S[3].w;                           \
} while (0)

#define SB __builtin_amdgcn_sched_barrier(0)

// ---------------------------------------------------------------------------
// Kernel 1: per (group g, chunk cg of 256 rows); each of 4 waves streams 64
// rows in 8 software-pipelined stages. One barrier total (cross-wave merge).
// Grid (16, 64), 256 threads, 4 blocks/CU.
// ---------------------------------------------------------------------------
__global__ __launch_bounds__(256, 4) void lqa_fused_kernel(
    const float* __restrict__ keys, const float* __restrict__ k_bias,
    const float* __restrict__ values, const float* __restrict__ v_bias,
    const float* __restrict__ query, const float* __restrict__ sw,
    const float* __restrict__ sb, float* __restrict__ partials,
    float* __restrict__ zstats)
{
    const int cg = blockIdx.x;               // 0..15
    const int g  = blockIdx.y;               // 0..63
    const int b = g >> 3, h = g & 7;
    const int t = threadIdx.x;
    const int w = t >> 6;                    // wave 0..3
    const int lane = t & 63;
    const int R0 = cg * 256 + w * 64;        // this wave's 64 rows

    __shared__ float red[4 * DV];
    __shared__ float zred[4];

    const int gid = lane >> 4, l16 = lane & 15;     // K-phase lane mapping
    const int hi = (lane >> 5) & 1;                  // V-phase lane mapping
    const int d0 = (lane & 31) * 4;

    const float* kp = keys + (long long)b * (LSEQ * KDIM);
    const float* vp = values + (long long)b * (LSEQ * EDIM);
    const int fheadk = h * (LP * DK);
    const int fheadv = h * (LP * DV);
    const float* wptr = sw + h * LP;
    const float* bptr = sb + h * LP;
    const floatx4 q = *reinterpret_cast<const floatx4*>(query + h * DK + l16 * 4);

    floatx4 kv0A, kv1A, vvA[4];
    floatx4 kv0B, kv1B, vvB[4];
    float wv0A, wv1A, bv0A, bv1A;
    float wv0B, wv1B, bv0B, bv1B;
    float a0 = 0.f, a1 = 0.f, a2 = 0.f, a3 = 0.f, z = 0.f;

    // -------- software-pipelined stream over 8 stages of 8 rows --------
    STAGE_LOAD(A, R0 + 0);
    STAGE_LOAD(B, R0 + 8);
    SB;
    STAGE_COMPUTE(A);
    STAGE_LOAD(A, R0 + 16); SB; STAGE_COMPUTE(B);
    STAGE_LOAD(B, R0 + 24); SB; STAGE_COMPUTE(A);
    STAGE_LOAD(A, R0 + 32); SB; STAGE_COMPUTE(B);
    STAGE_LOAD(B, R0 + 40); SB; STAGE_COMPUTE(A);
    STAGE_LOAD(A, R0 + 48); SB; STAGE_COMPUTE(B);
    STAGE_LOAD(B, R0 + 56); SB; STAGE_COMPUTE(A);
    SB;
    STAGE_COMPUTE(B);

    // fold even/odd row parity: all lanes hold dims (lane&31)*4 summed
    a0 += __shfl_xor(a0, 32);
    a1 += __shfl_xor(a1, 32);
    a2 += __shfl_xor(a2, 32);
    a3 += __shfl_xor(a3, 32);
    // wave z: fold the 4 groups
    z += __shfl_xor(z, 16);
    z += __shfl_xor(z, 32);

    // ---- tail: merge the 4 waves' partials (single barrier) ----
    if (lane < 32) {
        float* dst = red + w * DV + d0;
        dst[0] = a0; dst[1] = a1; dst[2] = a2; dst[3] = a3;
    }
    if (lane == 0) zred[w] = z;
    __syncthreads();
    if (t < DV) {
        const float sum = red[t] + red[DV + t] + red[2 * DV + t] + red[3 * DV + t];
        partials[((long long)(g * NCH + cg)) * DV + t] = sum;
    } else if (t == DV) {
        zstats[g * NCH + cg] = zred[0] + zred[1] + zred[2] + zred[3];
    }
}

// ---------------------------------------------------------------------------
// Kernel 2: combine (m=0 frame: plain sums) + row-4096 token + LayerNorm.
// One block per batch, 1024 threads (one per embed dim). NCH=16 version.
// ---------------------------------------------------------------------------
__global__ __launch_bounds__(1024) void lqa_combine_ln_kernel(
    const float* __restrict__ partials, const float* __restrict__ zstats,
    const float* __restrict__ keys, const float* __restrict__ values,
    const float* __restrict__ k_bias, const float* __restrict__ v_bias,
    const float* __restrict__ query, const float* __restrict__ sw,
    const float* __restrict__ sb, const float* __restrict__ gamma,
    const float* __restrict__ beta, float* __restrict__ out)
{
    const int b = blockIdx.x;
    const int t = threadIdx.x;
    __shared__ float zh[NH];                 // per-head Z (finally incl. e_bias)
    __shared__ float eb[NH];                 // row-4096 exp weight per head
    __shared__ float r1[16], r2[16];

    // S1 (threads 0-127): Z = sum_c z_c; 16 chunks per head, 16-lane groups
    if (t < 128) {
        float zv = zstats[(b * NH + (t >> 4)) * NCH + (t & 15)];
        zv += __shfl_xor(zv, 1);
        zv += __shfl_xor(zv, 2);
        zv += __shfl_xor(zv, 4);
        zv += __shfl_xor(zv, 8);
        if ((t & 15) == 0) zh[t >> 4] = zv;
    } else if (t < 256) {
        // S2 (threads 128-255): row-4096 score per head: 16-lane dot + exp
        const int tt = t - 128;
        const int h = tt >> 4, l16 = tt & 15;
        const floatx4 q = *reinterpret_cast<const floatx4*>(query + h * DK + l16 * 4);
        const int fk = h * (LP * DK) + LSEQ * DK;       // flat row 4096
        const float* kr = (fk < KLIM)
            ? keys + (long long)b * (LSEQ * KDIM) + fk
            : k_bias + (fk - KLIM);
        const floatx4 k = *reinterpret_cast<const floatx4*>(kr + l16 * 4);
        float s = q.x * k.x + q.y * k.y + q.z * k.z + q.w * k.w;
        s += __shfl_xor(s, 1);
        s += __shfl_xor(s, 2);
        s += __shfl_xor(s, 4);
        s += __shfl_xor(s, 8);
        if (l16 == 0) eb[h] = __expf(s * sw[h * LP + LSEQ] + sb[h * LP + LSEQ]);
    }
    __syncthreads();
    if (t < NH) zh[t] += eb[t];
    __syncthreads();

    // S3: each thread owns one embed dim e = t = h*128 + d
    const int h = t >> 7, d = t & 127;
    const float* src = partials + ((long long)((b * NH + h) * NCH)) * DV + d;
    float sum = 0.f;
#pragma unroll
    for (int c = 0; c < NCH; ++c) sum += src[c * DV];
    const int fv = h * (LP * DV) + LSEQ * DV + d;       // flat row 4096
    const float v4 = (fv < VLIM)
        ? values[(long long)b * (LSEQ * EDIM) + fv]
        : v_bias[fv - VLIM];
    const float av = (sum + eb[h] * v4) / zh[h];

    // S4: LayerNorm over 1024 dims: wave shuffle reduce + 16-wave LDS combine
    float s1 = av, s2 = av * av;
    s1 += __shfl_xor(s1, 1);  s2 += __shfl_xor(s2, 1);
    s1 += __shfl_xor(s1, 2);  s2 += __shfl_xor(s2, 2);
    s1 += __shfl_xor(s1, 4);  s2 += __shfl_xor(s2, 4);
    s1 += __shfl_xor(s1, 8);  s2 += __shfl_xor(s2, 8);
    s1 += __shfl_xor(s1, 16); s2 += __shfl_xor(s2, 16);
    s1 += __shfl_xor(s1, 32); s2 += __shfl_xor(s2, 32);
    if ((t & 63) == 0) { r1[t >> 6] = s1; r2[t >> 6] = s2; }
    __syncthreads();
    float fs1 = 0.f, fs2 = 0.f;
#pragma unroll
    for (int i = 0; i < 16; ++i) { fs1 += r1[i]; fs2 += r2[i]; }
    const float mean = fs1 * (1.0f / EDIM);
    const float var = fs2 * (1.0f / EDIM) - mean * mean;
    const float inv = rsqrtf(var + LN_EPS);
    out[(long long)b * EDIM + t] = (av - mean) * inv * gamma[t] + beta[t];
}

// ---------------------------------------------------------------------------
extern "C" void kernel_launch(void* const* d_in, const int* in_sizes, int n_in,
                              void* d_out, int out_size, void* d_ws, size_t ws_size,
                              hipStream_t stream) {
    const float* keys   = (const float*)d_in[0];
    const float* values = (const float*)d_in[1];
    const float* query  = (const float*)d_in[2];
    const float* k_bias = (const float*)d_in[3];
    const float* v_bias = (const float*)d_in[4];
    const float* sw     = (const float*)d_in[5];
    const float* sb     = (const float*)d_in[6];
    const float* gamma  = (const float*)d_in[7];
    const float* beta   = (const float*)d_in[8];
    float* out = (float*)d_out;

    // ws layout (floats): partials[64][16][128] | zstats[64*16] (~520 KB)
    float* ws = (float*)d_ws;
    float* partials = ws;
    float* zstats = ws + (long long)NG * NCH * DV;

    lqa_fused_kernel<<<dim3(NCH, NG), 256, 0, stream>>>(
        keys, k_bias, values, v_bias, query, sw, sb, partials, zstats);
    lqa_combine_ln_kernel<<<BATCH, 1024, 0, stream>>>(
        partials, zstats, keys, values, k_bias, v_bias, query, sw, sb,
        gamma, beta, out);
}

// Round 6
// 252.378 us; speedup vs baseline: 1.0930x; 1.0930x over previous
//
#include <hip/hip_runtime.h>

// LearnedQueryAttention: B=8, L=4096, KD=512, ED=1024, H=8. All I/O fp32.
// Raw-reshape semantics: head h owns the contiguous flat slab
// f = h*(L+1)*(C/H) + row*(C/H) + d of per-batch [X_flat | bias]; only
// f >= L*C touches the bias token (head 7, rows 4089..4096). Row-aligned
// pointer select is exact for both K (64 f/row) and V (128 f/row).
//
// Round notes (this revision):
//  - R5 post-mortem: forced 2-stage pipeline DID materialize (VGPR 32->64,
//    HBM 1.3->2.08 TB/s) but spilled ~280 B/thread (WRITE_SIZE 1->74 MB):
//    footprint ~100 VGPR vs allocator's chosen 64. Fix: SPLIT k1 into two
//    pure streamers whose pipelined state fits under 64 VGPR:
//    * Kernel A (scores): K-stream, 2-deep pipeline, stage = 1 K-row +
//      w + b (~6 VGPR). Writes e[64][4096] (1 MB) to ws. ~30 VGPR.
//    * Kernel B (AV): V-stream, NO shuffles/exp in the loop. e-chunk staged
//      in LDS; acc += e[r]*V[r][d]; 2-deep x 4-wide pipeline (stage 20
//      VGPR, total ~56). grid (16,64) = 4 blocks/CU. 4-8 loads in
//      flight/wave x 16 waves/CU >> Little's-law need.
//    * Verification: B WRITE_SIZE must be ~0.6 MB (no spill). If clean and
//      still <=2.7 TB/s effective -> pattern ceiling, declare floor.
//  - m=0 softmax frame retained (|scores|<~1): no max pass, partials sum
//    directly. Row 4096 handled analytically in kernel C.
#define BATCH 8
#define LSEQ  4096
#define LP    4097
#define KDIM  512
#define EDIM  1024
#define NH    8
#define DK    64
#define DV    128
#define NG    64          // B*H groups
#define NCH   16          // chunks per group (256 rows each) for B/C
#define KLIM  (LSEQ * KDIM)
#define VLIM  (LSEQ * EDIM)
#define LN_EPS 1e-5f

typedef float floatx4 __attribute__((ext_vector_type(4)));

#define SB __builtin_amdgcn_sched_barrier(0)

// ===========================================================================
// Kernel A: scores. grid (32, 64), 256 thr. Block = (chunk of 128 rows,
// group). 16 groups of 16 lanes; each group 1 row/stage; 8 stages,
// 2-deep software pipeline. e[row] = exp(dot64(q,K_row)*w+b) -> ws.
// ===========================================================================
#define ALOAD(S, rr) do {                                                   \
    const int row = (rr) + gid;                                             \
    const int f = fheadk + row * DK;                                        \
    const float* p = (f < KLIM) ? (kp + f) : (k_bias + (f - KLIM));         \
    kv##S = *reinterpret_cast<const floatx4*>(p + l16 * 4);                 \
    wv##S = wptr[row]; bv##S = bptr[row];                                   \
} while (0)

#define ACOMP(S, rr) do {                                                   \
    float s = q.x * kv##S.x + q.y * kv##S.y + q.z * kv##S.z + q.w * kv##S.w;\
    s += __shfl_xor(s, 1);                                                  \
    s += __shfl_xor(s, 2);                                                  \
    s += __shfl_xor(s, 4);                                                  \
    s += __shfl_xor(s, 8);                                                  \
    if (l16 == 0) eout[(rr) + gid] = __expf(s * wv##S + bv##S);             \
} while (0)

__global__ __launch_bounds__(256, 4) void lqa_scores_kernel(
    const float* __restrict__ keys, const float* __restrict__ k_bias,
    const float* __restrict__ query, const float* __restrict__ sw,
    const float* __restrict__ sb, float* __restrict__ e)
{
    const int g = blockIdx.y;                // 0..63
    const int b = g >> 3, h = g & 7;
    const int t = threadIdx.x;
    const int gid = t >> 4, l16 = t & 15;    // 16 groups x 16 lanes
    const int row0 = blockIdx.x * 128;

    const float* kp = keys + (long long)b * (LSEQ * KDIM);
    const int fheadk = h * (LP * DK);
    const float* wptr = sw + h * LP;
    const float* bptr = sb + h * LP;
    float* eout = e + (long long)g * LSEQ;
    const floatx4 q = *reinterpret_cast<const floatx4*>(query + h * DK + l16 * 4);

    floatx4 kvA, kvB;
    float wvA, bvA, wvB, bvB;

    ALOAD(A, row0 + 0); ALOAD(B, row0 + 16); SB;
    ACOMP(A, row0 + 0);   ALOAD(A, row0 + 32);  SB;
    ACOMP(B, row0 + 16);  ALOAD(B, row0 + 48);  SB;
    ACOMP(A, row0 + 32);  ALOAD(A, row0 + 64);  SB;
    ACOMP(B, row0 + 48);  ALOAD(B, row0 + 80);  SB;
    ACOMP(A, row0 + 64);  ALOAD(A, row0 + 96);  SB;
    ACOMP(B, row0 + 80);  ALOAD(B, row0 + 112); SB;
    ACOMP(A, row0 + 96);  SB;
    ACOMP(B, row0 + 112);
}

// ===========================================================================
// Kernel B: AV stream. grid (16, 64), 256 thr, 4 blocks/CU. Block =
// (chunk of 256 rows, group). srow = t>>5 (8 row-streams), d0=(t&31)*4.
// e-chunk staged in LDS; 32 iterations, 2-deep x 4-wide pipeline.
// Outputs partials[g][cg][128] + zstats[g][cg].
// ===========================================================================
#define BLOAD(S, i0) do {                                                   \
    _Pragma("unroll")                                                       \
    for (int j = 0; j < 4; ++j) {                                           \
        const int row = row0 + srow + 8 * ((i0) + j);                       \
        const int f = fheadv + row * DV;                                    \
        const float* p = (f < VLIM) ? (vp + f) : (v_bias + (f - VLIM));     \
        vv##S[j] = *reinterpret_cast<const floatx4*>(p + d0);               \
        ev##S[j] = es[srow + 8 * ((i0) + j)];                               \
    }                                                                       \
} while (0)

#define BCOMP(S) do {                                                       \
    _Pragma("unroll")                                                       \
    for (int j = 0; j < 4; ++j) {                                           \
        a0 += ev##S[j] * vv##S[j].x; a1 += ev##S[j] * vv##S[j].y;           \
        a2 += ev##S[j] * vv##S[j].z; a3 += ev##S[j] * vv##S[j].w;           \
    }                                                                       \
} while (0)

__global__ __launch_bounds__(256, 4) void lqa_av_kernel(
    const float* __restrict__ values, const float* __restrict__ v_bias,
    const float* __restrict__ e, float* __restrict__ partials,
    float* __restrict__ zstats)
{
    const int cg = blockIdx.x;               // 0..15
    const int g  = blockIdx.y;               // 0..63
    const int b = g >> 3, h = g & 7;
    const int t = threadIdx.x;
    const int w = t >> 6;
    const int lane = t & 63;
    const int srow = t >> 5;                 // 0..7
    const int d0 = (t & 31) * 4;
    const int row0 = cg * 256;

    __shared__ float es[256];
    __shared__ float red[4 * DV];

    const float* vp = values + (long long)b * (LSEQ * EDIM);
    const int fheadv = h * (LP * DV);

    // stage e-chunk (coalesced 1 KB/wave)
    es[t] = e[(long long)g * LSEQ + row0 + t];
    __syncthreads();

    floatx4 vvA[4], vvB[4];
    float evA[4], evB[4];
    float a0 = 0.f, a1 = 0.f, a2 = 0.f, a3 = 0.f;

    BLOAD(A, 0); BLOAD(B, 4); SB;
    BCOMP(A); BLOAD(A, 8);  SB;
    BCOMP(B); BLOAD(B, 12); SB;
    BCOMP(A); BLOAD(A, 16); SB;
    BCOMP(B); BLOAD(B, 20); SB;
    BCOMP(A); BLOAD(A, 24); SB;
    BCOMP(B); BLOAD(B, 28); SB;
    BCOMP(A); SB;
    BCOMP(B);

    // fold srow pairs within each wave: lanes 0-31 hold dims d0 summed
    a0 += __shfl_xor(a0, 32);
    a1 += __shfl_xor(a1, 32);
    a2 += __shfl_xor(a2, 32);
    a3 += __shfl_xor(a3, 32);

    // z for this chunk (wave 0; es stable)
    float zp = 0.f;
    if (t < 64) zp = es[t] + es[t + 64] + es[t + 128] + es[t + 192];

    if (lane < 32) {
        float* dst = red + w * DV + d0;
        dst[0] = a0; dst[1] = a1; dst[2] = a2; dst[3] = a3;
    }
    __syncthreads();
    if (t < DV) {
        const float sum = red[t] + red[DV + t] + red[2 * DV + t] + red[3 * DV + t];
        partials[((long long)(g * NCH + cg)) * DV + t] = sum;
    }
    if (t < 64) {
        zp += __shfl_xor(zp, 1);
        zp += __shfl_xor(zp, 2);
        zp += __shfl_xor(zp, 4);
        zp += __shfl_xor(zp, 8);
        zp += __shfl_xor(zp, 16);
        zp += __shfl_xor(zp, 32);
        if (t == 0) zstats[g * NCH + cg] = zp;
    }
}

// ===========================================================================
// Kernel C: combine (m=0 frame: plain sums) + row-4096 token + LayerNorm.
// One block per batch, 1024 threads (one per embed dim). NCH=16.
// ===========================================================================
__global__ __launch_bounds__(1024) void lqa_combine_ln_kernel(
    const float* __restrict__ partials, const float* __restrict__ zstats,
    const float* __restrict__ keys, const float* __restrict__ values,
    const float* __restrict__ k_bias, const float* __restrict__ v_bias,
    const float* __restrict__ query, const float* __restrict__ sw,
    const float* __restrict__ sb, const float* __restrict__ gamma,
    const float* __restrict__ beta, float* __restrict__ out)
{
    const int b = blockIdx.x;
    const int t = threadIdx.x;
    __shared__ float zh[NH];                 // per-head Z (finally incl. e_bias)
    __shared__ float eb[NH];                 // row-4096 exp weight per head
    __shared__ float r1[16], r2[16];

    // S1 (threads 0-127): Z = sum_c z_c; 16 chunks per head, 16-lane groups
    if (t < 128) {
        float zv = zstats[(b * NH + (t >> 4)) * NCH + (t & 15)];
        zv += __shfl_xor(zv, 1);
        zv += __shfl_xor(zv, 2);
        zv += __shfl_xor(zv, 4);
        zv += __shfl_xor(zv, 8);
        if ((t & 15) == 0) zh[t >> 4] = zv;
    } else if (t < 256) {
        // S2 (threads 128-255): row-4096 score per head: 16-lane dot + exp
        const int tt = t - 128;
        const int h = tt >> 4, l16 = tt & 15;
        const floatx4 q = *reinterpret_cast<const floatx4*>(query + h * DK + l16 * 4);
        const int fk = h * (LP * DK) + LSEQ * DK;       // flat row 4096
        const float* kr = (fk < KLIM)
            ? keys + (long long)b * (LSEQ * KDIM) + fk
            : k_bias + (fk - KLIM);
        const floatx4 k = *reinterpret_cast<const floatx4*>(kr + l16 * 4);
        float s = q.x * k.x + q.y * k.y + q.z * k.z + q.w * k.w;
        s += __shfl_xor(s, 1);
        s += __shfl_xor(s, 2);
        s += __shfl_xor(s, 4);
        s += __shfl_xor(s, 8);
        if (l16 == 0) eb[h] = __expf(s * sw[h * LP + LSEQ] + sb[h * LP + LSEQ]);
    }
    __syncthreads();
    if (t < NH) zh[t] += eb[t];
    __syncthreads();

    // S3: each thread owns one embed dim e = t = h*128 + d
    const int h = t >> 7, d = t & 127;
    const float* src = partials + ((long long)((b * NH + h) * NCH)) * DV + d;
    float sum = 0.f;
#pragma unroll
    for (int c = 0; c < NCH; ++c) sum += src[c * DV];
    const int fv = h * (LP * DV) + LSEQ * DV + d;       // flat row 4096
    const float v4 = (fv < VLIM)
        ? values[(long long)b * (LSEQ * EDIM) + fv]
        : v_bias[fv - VLIM];
    const float av = (sum + eb[h] * v4) / zh[h];

    // S4: LayerNorm over 1024 dims: wave shuffle reduce + 16-wave LDS combine
    float s1 = av, s2 = av * av;
    s1 += __shfl_xor(s1, 1);  s2 += __shfl_xor(s2, 1);
    s1 += __shfl_xor(s1, 2);  s2 += __shfl_xor(s2, 2);
    s1 += __shfl_xor(s1, 4);  s2 += __shfl_xor(s2, 4);
    s1 += __shfl_xor(s1, 8);  s2 += __shfl_xor(s2, 8);
    s1 += __shfl_xor(s1, 16); s2 += __shfl_xor(s2, 16);
    s1 += __shfl_xor(s1, 32); s2 += __shfl_xor(s2, 32);
    if ((t & 63) == 0) { r1[t >> 6] = s1; r2[t >> 6] = s2; }
    __syncthreads();
    float fs1 = 0.f, fs2 = 0.f;
#pragma unroll
    for (int i = 0; i < 16; ++i) { fs1 += r1[i]; fs2 += r2[i]; }
    const float mean = fs1 * (1.0f / EDIM);
    const float var = fs2 * (1.0f / EDIM) - mean * mean;
    const float inv = rsqrtf(var + LN_EPS);
    out[(long long)b * EDIM + t] = (av - mean) * inv * gamma[t] + beta[t];
}

// ---------------------------------------------------------------------------
extern "C" void kernel_launch(void* const* d_in, const int* in_sizes, int n_in,
                              void* d_out, int out_size, void* d_ws, size_t ws_size,
                              hipStream_t stream) {
    const float* keys   = (const float*)d_in[0];
    const float* values = (const float*)d_in[1];
    const float* query  = (const float*)d_in[2];
    const float* k_bias = (const float*)d_in[3];
    const float* v_bias = (const float*)d_in[4];
    const float* sw     = (const float*)d_in[5];
    const float* sb     = (const float*)d_in[6];
    const float* gamma  = (const float*)d_in[7];
    const float* beta   = (const float*)d_in[8];
    float* out = (float*)d_out;

    // ws layout (floats):
    //   partials[64][16][128] (131072) | zstats[1024] | e[64][4096] (262144)
    float* ws = (float*)d_ws;
    float* partials = ws;
    float* zstats = ws + (long long)NG * NCH * DV;
    float* e = zstats + NG * NCH;

    lqa_scores_kernel<<<dim3(32, NG), 256, 0, stream>>>(
        keys, k_bias, query, sw, sb, e);
    lqa_av_kernel<<<dim3(NCH, NG), 256, 0, stream>>>(
        values, v_bias, e, partials, zstats);
    lqa_combine_ln_kernel<<<BATCH, 1024, 0, stream>>>(
        partials, zstats, keys, values, k_bias, v_bias, query, sw, sb,
        gamma, beta, out);
}